// Round 6
// baseline (266.501 us; speedup 1.0000x reference)
//
#include <hip/hip_runtime.h>
#include <stdint.h>

static constexpr int kN   = 50000;   // nodes
static constexpr int kCap = 64;      // adjacency capacity per node (Poisson(12) tail @64 ~ 1e-25)

// ---------------- threefry2x32-20 (verified vs Random123 KAT) ----------------
__device__ __forceinline__ uint32_t rotl32(uint32_t v, uint32_t r) {
  return (v << r) | (v >> (32u - r));
}

__device__ __forceinline__ uint2 threefry2x32(uint32_t k0, uint32_t k1,
                                              uint32_t x0, uint32_t x1) {
  const uint32_t k2 = k0 ^ k1 ^ 0x1BD11BDAu;
  x0 += k0; x1 += k1;
#define TFR(r) { x0 += x1; x1 = rotl32(x1, r); x1 ^= x0; }
  TFR(13u) TFR(15u) TFR(26u) TFR(6u)
  x0 += k1; x1 += k2 + 1u;
  TFR(17u) TFR(29u) TFR(16u) TFR(24u)
  x0 += k2; x1 += k0 + 2u;
  TFR(13u) TFR(15u) TFR(26u) TFR(6u)
  x0 += k0; x1 += k1 + 3u;
  TFR(17u) TFR(29u) TFR(16u) TFR(24u)
  x0 += k1; x1 += k2 + 4u;
  TFR(13u) TFR(15u) TFR(26u) TFR(6u)
  x0 += k2; x1 += k0 + 5u;
#undef TFR
  return make_uint2(x0, x1);
}

// JAX dropout bit (jax_threefry_partitionable default): keep iff MSB==0 of
// out0^out1 of threefry((0,42), (0, j)).
__device__ __forceinline__ bool drop_elem(uint32_t j) {
  const uint2 r = threefry2x32(0u, 42u, 0u, j);
  return ((r.x ^ r.y) >> 31) != 0u;
}

// ---------------- bf16 pack/unpack ----------------
__device__ __forceinline__ uint32_t bf16_rtne(float f) {
  uint32_t u = __float_as_uint(f);
  u += 0x7fffu + ((u >> 16) & 1u);
  return u >> 16;
}
__device__ __forceinline__ uint32_t pack_bf16x2(float lo, float hi) {
  return bf16_rtne(lo) | (bf16_rtne(hi) << 16);
}
__device__ __forceinline__ float unpk_lo(uint32_t u) { return __uint_as_float(u << 16); }
__device__ __forceinline__ float unpk_hi(uint32_t u) { return __uint_as_float(u & 0xffff0000u); }
// variable-select unpack: sh = 0 (low half) or 16 (high half)
__device__ __forceinline__ float unpk_sh(uint32_t u, uint32_t sh) {
  return __uint_as_float((u >> sh) << 16);
}

// ---------------- adjacency build: adj[d*64 + slot] = src ----------------
__global__ __launch_bounds__(256) void build_adj(
    const int* __restrict__ src, const int* __restrict__ dst,
    int* __restrict__ cnt, int* __restrict__ adj, int E) {
  int e = blockIdx.x * 256 + threadIdx.x;
  if (e >= E) return;
  int d = dst[e];
  int slot = atomicAdd(&cnt[d], 1);
  if (slot < kCap) adj[d * kCap + slot] = src[e];
}

// ---------------- dense GEMM 1: z1b = pack_bf16(x @ W1) ----------------
// Block 256 = 4 waves; each wave computes 4 nodes. Lane holds output features
// {2l, 2l+1}. W1 in LDS as float4. Input row broadcast via v_readlane.
__global__ __launch_bounds__(256, 2) void gemm1(
    const float* __restrict__ x, const float* __restrict__ W1,
    uint32_t* __restrict__ z1b) {
  __shared__ float4 Wq[64 * 64];  // 64 KB
  for (int idx = threadIdx.x; idx < 64 * 64; idx += 256) {
    const int kk = idx >> 6, l = idx & 63;
    const float2 a = *reinterpret_cast<const float2*>(W1 + (size_t)(2 * kk) * 128 + 2 * l);
    const float2 b = *reinterpret_cast<const float2*>(W1 + (size_t)(2 * kk + 1) * 128 + 2 * l);
    Wq[idx] = make_float4(a.x, a.y, b.x, b.y);
  }
  __syncthreads();

  const int lane = threadIdx.x & 63;
  const int wid  = threadIdx.x >> 6;
  const int n0 = (blockIdx.x * 4 + wid) * 4;  // 3125 blocks * 16 = 50000 exact

  float rx[4], ry[4];
#pragma unroll
  for (int i = 0; i < 4; ++i) {
    const float2 v = *reinterpret_cast<const float2*>(x + (size_t)(n0 + i) * 128 + 2 * lane);
    rx[i] = v.x; ry[i] = v.y;
  }
  float ax[4] = {0.f, 0.f, 0.f, 0.f}, ay[4] = {0.f, 0.f, 0.f, 0.f};
#pragma unroll
  for (int kk = 0; kk < 64; ++kk) {
    const float4 w = Wq[kk * 64 + lane];
#pragma unroll
    for (int i = 0; i < 4; ++i) {
      const float v0 = __int_as_float(__builtin_amdgcn_readlane(__float_as_int(rx[i]), kk));
      const float v1 = __int_as_float(__builtin_amdgcn_readlane(__float_as_int(ry[i]), kk));
      ax[i] = fmaf(v0, w.x, ax[i]); ay[i] = fmaf(v0, w.y, ay[i]);
      ax[i] = fmaf(v1, w.z, ax[i]); ay[i] = fmaf(v1, w.w, ay[i]);
    }
  }
#pragma unroll
  for (int i = 0; i < 4; ++i)
    z1b[(size_t)(n0 + i) * 64 + lane] = pack_bf16x2(ax[i], ay[i]);
}

// ---------------- agg1 + gemm2 fused ----------------
// h[n] = dropout(relu(z1[n] + sum z1[adj] + b1))   (in registers)
// z2[n] = h[n] @ W2                                 (written packed bf16)
// One node per wave; gather = 1 dword/lane/row (256 B), 16 rows in flight.
__global__ __launch_bounds__(256, 5) void agg1_fused(
    const uint32_t* __restrict__ z1b, const int* __restrict__ adj,
    const int* __restrict__ cnt, const float* __restrict__ b1,
    const float* __restrict__ W2, const uint32_t* __restrict__ zpad,
    uint32_t* __restrict__ z2b) {
  __shared__ float2 Wl[64 * 64];  // 32 KB: Wl[kk*64+o] = {W2[2kk][o], W2[2kk+1][o]}
  for (int idx = threadIdx.x; idx < 64 * 64; idx += 256) {
    const int kk = idx >> 6, l = idx & 63;
    Wl[idx] = make_float2(W2[(size_t)(2 * kk) * 64 + l], W2[(size_t)(2 * kk + 1) * 64 + l]);
  }
  __syncthreads();

  const int lane = threadIdx.x & 63;
  const int wid  = threadIdx.x >> 6;
  const int n = blockIdx.x * 4 + wid;

  const int va = adj[(size_t)n * kCap + lane];
  int d = __builtin_amdgcn_readfirstlane(cnt[n]);
  if (d > kCap) d = kCap;

  // self term (features {2l, 2l+1} packed in one dword)
  const uint32_t self = z1b[(size_t)n * 64 + lane];
  float a0x = unpk_lo(self), a0y = unpk_hi(self);
  float a1x = 0.f, a1y = 0.f, a2x = 0.f, a2y = 0.f, a3x = 0.f, a3y = 0.f;

  int e = 0;
  while (e < d) {
#pragma unroll
    for (int j = 0; j < 16; ++j) {
      const int ee = e + j;
      const int idx = __builtin_amdgcn_readlane(va, ee);
      const uint32_t* base = (ee < d) ? (z1b + (size_t)idx * 64) : zpad;  // scalar select
      const uint32_t v = base[lane];
      if ((j & 3) == 0)      { a0x += unpk_lo(v); a0y += unpk_hi(v); }
      else if ((j & 3) == 1) { a1x += unpk_lo(v); a1y += unpk_hi(v); }
      else if ((j & 3) == 2) { a2x += unpk_lo(v); a2y += unpk_hi(v); }
      else                   { a3x += unpk_lo(v); a3y += unpk_hi(v); }
    }
    e += 16;
  }

  const float2 bb = *reinterpret_cast<const float2*>(b1 + 2 * lane);
  float hx = fmaxf((a0x + a1x) + (a2x + a3x) + bb.x, 0.0f);
  float hy = fmaxf((a0y + a1y) + (a2y + a3y) + bb.y, 0.0f);
  const uint32_t j0 = (uint32_t)n * 128u + 2u * (uint32_t)lane;
  hx = drop_elem(j0)      ? 0.0f : hx * 2.0f;
  hy = drop_elem(j0 + 1u) ? 0.0f : hy * 2.0f;

  // z2[n][o] = sum_k h[k] * W2[k][o]; lane = o. h[2kk],h[2kk+1] live in lane kk.
  float acc = 0.f;
#pragma unroll
  for (int kk = 0; kk < 64; ++kk) {
    const float2 w = Wl[kk * 64 + lane];
    const float v0 = __int_as_float(__builtin_amdgcn_readlane(__float_as_int(hx), kk));
    const float v1 = __int_as_float(__builtin_amdgcn_readlane(__float_as_int(hy), kk));
    acc = fmaf(v0, w.x, acc);
    acc = fmaf(v1, w.y, acc);
  }

  // pack pairs of output features into dwords; even lanes store 32 dwords/row
  const float accOdd = __shfl(acc, lane | 1);
  if ((lane & 1) == 0)
    z2b[(size_t)n * 32 + (lane >> 1)] = pack_bf16x2(acc, accOdd);
}

// ---------------- agg2: out = z2[n] + sum z2[adj] + b2 (width 64, bf16 rows) ----------------
// Row = 32 dwords (128 B). Lanes 2i,2i+1 both load dword i (same line), each
// unpacks its half via per-lane shift.
__global__ __launch_bounds__(256, 8) void agg_out(
    const uint32_t* __restrict__ z2b, const int* __restrict__ adj,
    const int* __restrict__ cnt, const float* __restrict__ b2,
    const uint32_t* __restrict__ zpad, float* __restrict__ out) {
  const int lane = threadIdx.x & 63;
  const int wid  = threadIdx.x >> 6;
  const int n = blockIdx.x * 4 + wid;
  const uint32_t sh = (uint32_t)(lane & 1) * 16u;
  const int word = lane >> 1;

  const int va = adj[(size_t)n * kCap + lane];
  int d = __builtin_amdgcn_readfirstlane(cnt[n]);
  if (d > kCap) d = kCap;

  float a0 = unpk_sh(z2b[(size_t)n * 32 + word], sh);  // self
  float a1 = 0.f, a2 = 0.f, a3 = 0.f;

  int e = 0;
  while (e < d) {
#pragma unroll
    for (int j = 0; j < 16; ++j) {
      const int ee = e + j;
      const int idx = __builtin_amdgcn_readlane(va, ee);
      const uint32_t* base = (ee < d) ? (z2b + (size_t)idx * 32) : zpad;  // scalar select
      const float v = unpk_sh(base[word], sh);
      if ((j & 3) == 0)      a0 += v;
      else if ((j & 3) == 1) a1 += v;
      else if ((j & 3) == 2) a2 += v;
      else                   a3 += v;
    }
    e += 16;
  }

  out[(size_t)n * 64 + lane] = (a0 + a1) + (a2 + a3) + b2[lane];
}

// ---------------- launch ----------------
extern "C" void kernel_launch(void* const* d_in, const int* in_sizes, int n_in,
                              void* d_out, int out_size, void* d_ws, size_t ws_size,
                              hipStream_t stream) {
  const float* x  = (const float*)d_in[0];
  const int*   ei = (const int*)d_in[1];
  const float* W1 = (const float*)d_in[2];
  const float* b1 = (const float*)d_in[3];
  const float* W2 = (const float*)d_in[4];
  const float* b2 = (const float*)d_in[5];
  float* out = (float*)d_out;

  const int E = in_sizes[1] / 2;  // edge_index is (2, E), int32 on device
  const int* src = ei;
  const int* dst = ei + E;

  // d_ws layout:
  uint32_t* zpad = (uint32_t*)d_ws;                        // 64 dwords = 256 B, zeroed
  int*      cnt  = (int*)((char*)d_ws + 256);              // 50000 ints
  int*      adj  = cnt + kN;                               // 50000*64 ints = 12.8 MB
  uint32_t* z1b  = (uint32_t*)(adj + (size_t)kN * kCap);   // 50000*64 dwords = 12.8 MB
  uint32_t* z2b  = z1b + (size_t)kN * 64;                  // 50000*32 dwords = 6.4 MB

  hipMemsetAsync(d_ws, 0, 256 + (size_t)kN * sizeof(int), stream);  // zpad + cnt
  build_adj<<<(E + 255) / 256, 256, 0, stream>>>(src, dst, cnt, adj, E);
  gemm1<<<3125, 256, 0, stream>>>(x, W1, z1b);
  agg1_fused<<<12500, 256, 0, stream>>>(z1b, adj, cnt, b1, W2, zpad, z2b);
  agg_out<<<12500, 256, 0, stream>>>(z2b, adj, cnt, b2, zpad, out);
}

// Round 7
// 246.382 us; speedup vs baseline: 1.0817x; 1.0817x over previous
//
#include <hip/hip_runtime.h>
#include <stdint.h>

static constexpr int kN   = 50000;   // nodes
static constexpr int kCap = 64;      // adjacency capacity per node (Poisson(12) tail @64 ~ 1e-25)

// ---------------- threefry2x32-20 (verified vs Random123 KAT) ----------------
__device__ __forceinline__ uint32_t rotl32(uint32_t v, uint32_t r) {
  return (v << r) | (v >> (32u - r));
}

__device__ __forceinline__ uint2 threefry2x32(uint32_t k0, uint32_t k1,
                                              uint32_t x0, uint32_t x1) {
  const uint32_t k2 = k0 ^ k1 ^ 0x1BD11BDAu;
  x0 += k0; x1 += k1;
#define TFR(r) { x0 += x1; x1 = rotl32(x1, r); x1 ^= x0; }
  TFR(13u) TFR(15u) TFR(26u) TFR(6u)
  x0 += k1; x1 += k2 + 1u;
  TFR(17u) TFR(29u) TFR(16u) TFR(24u)
  x0 += k2; x1 += k0 + 2u;
  TFR(13u) TFR(15u) TFR(26u) TFR(6u)
  x0 += k0; x1 += k1 + 3u;
  TFR(17u) TFR(29u) TFR(16u) TFR(24u)
  x0 += k1; x1 += k2 + 4u;
  TFR(13u) TFR(15u) TFR(26u) TFR(6u)
  x0 += k2; x1 += k0 + 5u;
#undef TFR
  return make_uint2(x0, x1);
}

// JAX dropout bit (jax_threefry_partitionable default): keep iff MSB==0 of
// out0^out1 of threefry((0,42), (0, j)).
__device__ __forceinline__ bool drop_elem(uint32_t j) {
  const uint2 r = threefry2x32(0u, 42u, 0u, j);
  return ((r.x ^ r.y) >> 31) != 0u;
}

// ---------------- bf16 pack/unpack ----------------
__device__ __forceinline__ uint32_t bf16_rtne(float f) {
  uint32_t u = __float_as_uint(f);
  u += 0x7fffu + ((u >> 16) & 1u);
  return u >> 16;
}
__device__ __forceinline__ uint32_t pack_bf16x2(float lo, float hi) {
  return bf16_rtne(lo) | (bf16_rtne(hi) << 16);
}
__device__ __forceinline__ float unpk_lo(uint32_t u) { return __uint_as_float(u << 16); }
__device__ __forceinline__ float unpk_hi(uint32_t u) { return __uint_as_float(u & 0xffff0000u); }
__device__ __forceinline__ float unpk_sh(uint32_t u, uint32_t sh) {
  return __uint_as_float((u >> sh) << 16);
}

// ---------------- adjacency build: adj[d*64 + slot] = src ----------------
__global__ __launch_bounds__(256) void build_adj(
    const int* __restrict__ src, const int* __restrict__ dst,
    int* __restrict__ cnt, int* __restrict__ adj, int E) {
  int e = blockIdx.x * 256 + threadIdx.x;
  if (e >= E) return;
  int d = dst[e];
  int slot = atomicAdd(&cnt[d], 1);
  if (slot < kCap) adj[d * kCap + slot] = src[e];
}

// ---------------- dense GEMM 1: z1b = pack_bf16(x @ W1) ----------------
// 8 nodes per wave, 4 waves/block. W1 packed bf16 in LDS (32 KB -> 4 blocks/CU).
// Lane holds output features {2l, 2l+1}. Input broadcast via v_readlane.
__global__ __launch_bounds__(256, 4) void gemm1(
    const float* __restrict__ x, const float* __restrict__ W1,
    uint32_t* __restrict__ z1b) {
  __shared__ uint2 Wp[64 * 64];  // 32 KB: {pack(W[2kk][2l],W[2kk][2l+1]), pack(W[2kk+1][..])}
  for (int idx = threadIdx.x; idx < 64 * 64; idx += 256) {
    const int kk = idx >> 6, l = idx & 63;
    const float2 a = *reinterpret_cast<const float2*>(W1 + (size_t)(2 * kk) * 128 + 2 * l);
    const float2 b = *reinterpret_cast<const float2*>(W1 + (size_t)(2 * kk + 1) * 128 + 2 * l);
    Wp[idx] = make_uint2(pack_bf16x2(a.x, a.y), pack_bf16x2(b.x, b.y));
  }
  __syncthreads();

  const int lane = threadIdx.x & 63;
  const int wid  = threadIdx.x >> 6;
  const int n0 = (blockIdx.x * 4 + wid) * 8;  // 1563 blocks x 32 nodes (tail-guarded)

  float rx[8], ry[8];
#pragma unroll
  for (int i = 0; i < 8; ++i) {
    const int rn = (n0 + i < kN) ? (n0 + i) : (kN - 1);
    const float2 v = *reinterpret_cast<const float2*>(x + (size_t)rn * 128 + 2 * lane);
    rx[i] = v.x; ry[i] = v.y;
  }
  float ax[8], ay[8];
#pragma unroll
  for (int i = 0; i < 8; ++i) { ax[i] = 0.f; ay[i] = 0.f; }

#pragma unroll 16
  for (int kk = 0; kk < 64; ++kk) {
    const uint2 wp = Wp[kk * 64 + lane];
    const float w00 = unpk_lo(wp.x), w01 = unpk_hi(wp.x);
    const float w10 = unpk_lo(wp.y), w11 = unpk_hi(wp.y);
#pragma unroll
    for (int i = 0; i < 8; ++i) {
      const float v0 = __int_as_float(__builtin_amdgcn_readlane(__float_as_int(rx[i]), kk));
      const float v1 = __int_as_float(__builtin_amdgcn_readlane(__float_as_int(ry[i]), kk));
      ax[i] = fmaf(v0, w00, ax[i]); ay[i] = fmaf(v0, w01, ay[i]);
      ax[i] = fmaf(v1, w10, ax[i]); ay[i] = fmaf(v1, w11, ay[i]);
    }
  }
#pragma unroll
  for (int i = 0; i < 8; ++i)
    if (n0 + i < kN)
      z1b[(size_t)(n0 + i) * 64 + lane] = pack_bf16x2(ax[i], ay[i]);
}

// ---------------- agg1: hb = pack_bf16(dropout(relu(z1[n] + sum z1[adj] + b1))) ----------------
// Pure gather, no LDS. One node per wave, 16 rows in flight, 32 waves/CU.
__global__ __launch_bounds__(256, 8) void agg1(
    const uint32_t* __restrict__ z1b, const int* __restrict__ adj,
    const int* __restrict__ cnt, const float* __restrict__ b1,
    const uint32_t* __restrict__ zpad, uint32_t* __restrict__ hb) {
  const int lane = threadIdx.x & 63;
  const int wid  = threadIdx.x >> 6;
  const int n = blockIdx.x * 4 + wid;

  const int va = adj[(size_t)n * kCap + lane];
  int d = __builtin_amdgcn_readfirstlane(cnt[n]);
  if (d > kCap) d = kCap;

  const uint32_t self = z1b[(size_t)n * 64 + lane];
  float a0x = unpk_lo(self), a0y = unpk_hi(self);
  float a1x = 0.f, a1y = 0.f, a2x = 0.f, a2y = 0.f, a3x = 0.f, a3y = 0.f;

  int e = 0;
  while (e < d) {
#pragma unroll
    for (int j = 0; j < 16; ++j) {
      const int ee = e + j;
      const int idx = __builtin_amdgcn_readlane(va, ee);
      const uint32_t* base = (ee < d) ? (z1b + (size_t)idx * 64) : zpad;  // scalar select
      const uint32_t v = base[lane];
      if ((j & 3) == 0)      { a0x += unpk_lo(v); a0y += unpk_hi(v); }
      else if ((j & 3) == 1) { a1x += unpk_lo(v); a1y += unpk_hi(v); }
      else if ((j & 3) == 2) { a2x += unpk_lo(v); a2y += unpk_hi(v); }
      else                   { a3x += unpk_lo(v); a3y += unpk_hi(v); }
    }
    e += 16;
  }

  const float2 bb = *reinterpret_cast<const float2*>(b1 + 2 * lane);
  float hx = fmaxf((a0x + a1x) + (a2x + a3x) + bb.x, 0.0f);
  float hy = fmaxf((a0y + a1y) + (a2y + a3y) + bb.y, 0.0f);
  const uint32_t j0 = (uint32_t)n * 128u + 2u * (uint32_t)lane;
  hx = drop_elem(j0)      ? 0.0f : hx * 2.0f;
  hy = drop_elem(j0 + 1u) ? 0.0f : hy * 2.0f;
  hb[(size_t)n * 64 + lane] = pack_bf16x2(hx, hy);
}

// ---------------- dense GEMM 2: z2b = pack_bf16(h @ W2) ----------------
// 8 nodes per wave. h rows are packed bf16 (lane dword = features {2l,2l+1});
// readlane gives an SGPR, unpack stays on the scalar pipe. W2 f32 LDS (32 KB).
__global__ __launch_bounds__(256, 4) void gemm2(
    const uint32_t* __restrict__ hb, const float* __restrict__ W2,
    uint32_t* __restrict__ z2b) {
  __shared__ float2 Wl[64 * 64];  // 32 KB: Wl[kk*64+o] = {W2[2kk][o], W2[2kk+1][o]}
  for (int idx = threadIdx.x; idx < 64 * 64; idx += 256) {
    const int kk = idx >> 6, l = idx & 63;
    Wl[idx] = make_float2(W2[(size_t)(2 * kk) * 64 + l], W2[(size_t)(2 * kk + 1) * 64 + l]);
  }
  __syncthreads();

  const int lane = threadIdx.x & 63;
  const int wid  = threadIdx.x >> 6;
  const int n0 = (blockIdx.x * 4 + wid) * 8;  // 1563 blocks x 32 nodes (tail-guarded)

  uint32_t hw[8];
#pragma unroll
  for (int i = 0; i < 8; ++i) {
    const int rn = (n0 + i < kN) ? (n0 + i) : (kN - 1);
    hw[i] = hb[(size_t)rn * 64 + lane];
  }
  float acc[8];
#pragma unroll
  for (int i = 0; i < 8; ++i) acc[i] = 0.f;

#pragma unroll 16
  for (int kk = 0; kk < 64; ++kk) {
    const float2 w = Wl[kk * 64 + lane];
#pragma unroll
    for (int i = 0; i < 8; ++i) {
      const uint32_t s = (uint32_t)__builtin_amdgcn_readlane((int)hw[i], kk);
      acc[i] = fmaf(unpk_lo(s), w.x, acc[i]);
      acc[i] = fmaf(unpk_hi(s), w.y, acc[i]);
    }
  }
  // pack output-feature pairs into dwords; even lanes write 32 dwords/row
#pragma unroll
  for (int i = 0; i < 8; ++i) {
    const float accOdd = __shfl(acc[i], lane | 1);
    if ((lane & 1) == 0 && n0 + i < kN)
      z2b[(size_t)(n0 + i) * 32 + (lane >> 1)] = pack_bf16x2(acc[i], accOdd);
  }
}

// ---------------- agg2: out = z2[n] + sum z2[adj] + b2 (width 64, bf16 rows) ----------------
__global__ __launch_bounds__(256, 8) void agg_out(
    const uint32_t* __restrict__ z2b, const int* __restrict__ adj,
    const int* __restrict__ cnt, const float* __restrict__ b2,
    const uint32_t* __restrict__ zpad, float* __restrict__ out) {
  const int lane = threadIdx.x & 63;
  const int wid  = threadIdx.x >> 6;
  const int n = blockIdx.x * 4 + wid;
  const uint32_t sh = (uint32_t)(lane & 1) * 16u;
  const int word = lane >> 1;

  const int va = adj[(size_t)n * kCap + lane];
  int d = __builtin_amdgcn_readfirstlane(cnt[n]);
  if (d > kCap) d = kCap;

  float a0 = unpk_sh(z2b[(size_t)n * 32 + word], sh);  // self
  float a1 = 0.f, a2 = 0.f, a3 = 0.f;

  int e = 0;
  while (e < d) {
#pragma unroll
    for (int j = 0; j < 16; ++j) {
      const int ee = e + j;
      const int idx = __builtin_amdgcn_readlane(va, ee);
      const uint32_t* base = (ee < d) ? (z2b + (size_t)idx * 32) : zpad;  // scalar select
      const float v = unpk_sh(base[word], sh);
      if ((j & 3) == 0)      a0 += v;
      else if ((j & 3) == 1) a1 += v;
      else if ((j & 3) == 2) a2 += v;
      else                   a3 += v;
    }
    e += 16;
  }

  out[(size_t)n * 64 + lane] = (a0 + a1) + (a2 + a3) + b2[lane];
}

// ---------------- launch ----------------
extern "C" void kernel_launch(void* const* d_in, const int* in_sizes, int n_in,
                              void* d_out, int out_size, void* d_ws, size_t ws_size,
                              hipStream_t stream) {
  const float* x  = (const float*)d_in[0];
  const int*   ei = (const int*)d_in[1];
  const float* W1 = (const float*)d_in[2];
  const float* b1 = (const float*)d_in[3];
  const float* W2 = (const float*)d_in[4];
  const float* b2 = (const float*)d_in[5];
  float* out = (float*)d_out;

  const int E = in_sizes[1] / 2;  // edge_index is (2, E), int32 on device
  const int* src = ei;
  const int* dst = ei + E;

  // d_ws layout:
  uint32_t* zpad = (uint32_t*)d_ws;                        // 64 dwords = 256 B, zeroed
  int*      cnt  = (int*)((char*)d_ws + 256);              // 50000 ints
  int*      adj  = cnt + kN;                               // 50000*64 ints = 12.8 MB
  uint32_t* z1b  = (uint32_t*)(adj + (size_t)kN * kCap);   // 50000*64 dwords = 12.8 MB
  uint32_t* hb   = z1b + (size_t)kN * 64;                  // 50000*64 dwords = 12.8 MB
  uint32_t* z2b  = hb + (size_t)kN * 64;                   // 50000*32 dwords = 6.4 MB

  hipMemsetAsync(d_ws, 0, 256 + (size_t)kN * sizeof(int), stream);  // zpad + cnt
  build_adj<<<(E + 255) / 256, 256, 0, stream>>>(src, dst, cnt, adj, E);
  gemm1<<<1563, 256, 0, stream>>>(x, W1, z1b);
  agg1<<<12500, 256, 0, stream>>>(z1b, adj, cnt, b1, zpad, hb);
  gemm2<<<1563, 256, 0, stream>>>(hb, W2, z2b);
  agg_out<<<12500, 256, 0, stream>>>(z2b, adj, cnt, b2, zpad, out);
}

// Round 8
// 187.560 us; speedup vs baseline: 1.4209x; 1.3136x over previous
//
#include <hip/hip_runtime.h>
#include <stdint.h>

static constexpr int kN   = 50000;   // nodes
static constexpr int kCap = 64;      // adjacency capacity per node (Poisson(12) tail @64 ~ 1e-25)

typedef __attribute__((ext_vector_type(8))) short bf16x8;   // 8 bf16 = 4 VGPR
typedef __attribute__((ext_vector_type(4))) float f32x4;    // MFMA 16x16 accumulator

// ---------------- threefry2x32-20 (verified vs Random123 KAT) ----------------
__device__ __forceinline__ uint32_t rotl32(uint32_t v, uint32_t r) {
  return (v << r) | (v >> (32u - r));
}

__device__ __forceinline__ uint2 threefry2x32(uint32_t k0, uint32_t k1,
                                              uint32_t x0, uint32_t x1) {
  const uint32_t k2 = k0 ^ k1 ^ 0x1BD11BDAu;
  x0 += k0; x1 += k1;
#define TFR(r) { x0 += x1; x1 = rotl32(x1, r); x1 ^= x0; }
  TFR(13u) TFR(15u) TFR(26u) TFR(6u)
  x0 += k1; x1 += k2 + 1u;
  TFR(17u) TFR(29u) TFR(16u) TFR(24u)
  x0 += k2; x1 += k0 + 2u;
  TFR(13u) TFR(15u) TFR(26u) TFR(6u)
  x0 += k0; x1 += k1 + 3u;
  TFR(17u) TFR(29u) TFR(16u) TFR(24u)
  x0 += k1; x1 += k2 + 4u;
  TFR(13u) TFR(15u) TFR(26u) TFR(6u)
  x0 += k2; x1 += k0 + 5u;
#undef TFR
  return make_uint2(x0, x1);
}

__device__ __forceinline__ bool drop_elem(uint32_t j) {
  const uint2 r = threefry2x32(0u, 42u, 0u, j);
  return ((r.x ^ r.y) >> 31) != 0u;
}

// ---------------- bf16 pack/unpack ----------------
__device__ __forceinline__ uint32_t bf16_rtne(float f) {
  uint32_t u = __float_as_uint(f);
  u += 0x7fffu + ((u >> 16) & 1u);
  return u >> 16;
}
__device__ __forceinline__ uint32_t pack_bf16x2(float lo, float hi) {
  return bf16_rtne(lo) | (bf16_rtne(hi) << 16);
}
__device__ __forceinline__ float unpk_lo(uint32_t u) { return __uint_as_float(u << 16); }
__device__ __forceinline__ float unpk_hi(uint32_t u) { return __uint_as_float(u & 0xffff0000u); }
__device__ __forceinline__ float unpk_sh(uint32_t u, uint32_t sh) {
  return __uint_as_float((u >> sh) << 16);
}

union FragU { uint4 q; bf16x8 f; };

// ---------------- adjacency build: adj[d*64 + slot] = src ----------------
__global__ __launch_bounds__(256) void build_adj(
    const int* __restrict__ src, const int* __restrict__ dst,
    int* __restrict__ cnt, int* __restrict__ adj, int E) {
  int e = blockIdx.x * 256 + threadIdx.x;
  if (e >= E) return;
  int d = dst[e];
  int slot = atomicAdd(&cnt[d], 1);
  if (slot < kCap) adj[d * kCap + slot] = src[e];
}

// ---------------- prep: transpose+pack weights to bf16 ----------------
// W1T[n*64+i] = pack(W1[2i][n], W1[2i+1][n])   (n<128, i<64)
// W2T[n*64+i] = pack(W2[2i][n], W2[2i+1][n])   (n<64,  i<64)
__global__ __launch_bounds__(256) void prep_wT(
    const float* __restrict__ W1, const float* __restrict__ W2,
    uint32_t* __restrict__ W1T, uint32_t* __restrict__ W2T) {
  int v = blockIdx.x * 256 + threadIdx.x;
  if (v < 128 * 64) {
    const int n = v >> 6, i = v & 63;
    W1T[v] = pack_bf16x2(W1[(size_t)(2 * i) * 128 + n], W1[(size_t)(2 * i + 1) * 128 + n]);
  } else if (v < 128 * 64 + 64 * 64) {
    const int w = v - 128 * 64;
    const int n = w >> 6, i = w & 63;
    W2T[w] = pack_bf16x2(W2[(size_t)(2 * i) * 64 + n], W2[(size_t)(2 * i + 1) * 64 + n]);
  }
}

// ---------------- GEMM1 (MFMA): z1b = pack_bf16(x @ W1) ----------------
// Wave = 16 rows x 64 cols: 4 kb x 4 ct MFMAs. A: x converted to bf16 in-flight.
// B: W1T staged in LDS, row stride 68 dwords (bank stride 4 -> 2-way, free).
// Layouts (HW-verified): A[m=lane&15][k=quad*8+j], B[n=lane&15][k=quad*8+j],
// D: col=lane&15, row=quad*4+reg.
__global__ __launch_bounds__(256, 4) void gemm1_mfma(
    const float* __restrict__ x, const uint32_t* __restrict__ W1T,
    uint32_t* __restrict__ z1b) {
  __shared__ uint32_t WT[128 * 68];  // 34 KB
  for (int v = threadIdx.x; v < 128 * 64; v += 256)
    WT[(v >> 6) * 68 + (v & 63)] = W1T[v];
  __syncthreads();

  const int lane = threadIdx.x & 63;
  const int wid  = threadIdx.x >> 6;
  const int rb   = blockIdx.x * 2 + (wid >> 1);  // 1563 blocks -> rb 0..3125
  if (rb >= 3125) return;                        // tail wave (after LDS build)
  const int cg   = wid & 1;                      // column group: cols cg*64..+63
  const int n0   = rb * 16;
  const int quad = lane >> 4;
  const int mrow = lane & 15;

  const float* xp = x + (size_t)(n0 + mrow) * 128 + quad * 8;
  f32x4 acc[4] = {{0.f,0.f,0.f,0.f},{0.f,0.f,0.f,0.f},{0.f,0.f,0.f,0.f},{0.f,0.f,0.f,0.f}};

#pragma unroll
  for (int kb = 0; kb < 4; ++kb) {
    const float4 lo = *reinterpret_cast<const float4*>(xp + kb * 32);
    const float4 hi = *reinterpret_cast<const float4*>(xp + kb * 32 + 4);
    FragU a;
    a.q = make_uint4(pack_bf16x2(lo.x, lo.y), pack_bf16x2(lo.z, lo.w),
                     pack_bf16x2(hi.x, hi.y), pack_bf16x2(hi.z, hi.w));
#pragma unroll
    for (int ct = 0; ct < 4; ++ct) {
      const int n = cg * 64 + ct * 16 + mrow;
      FragU b;
      b.q = *reinterpret_cast<const uint4*>(&WT[n * 68 + kb * 16 + quad * 4]);
      acc[ct] = __builtin_amdgcn_mfma_f32_16x16x32_bf16(a.f, b.f, acc[ct], 0, 0, 0);
    }
  }

#pragma unroll
  for (int ct = 0; ct < 4; ++ct) {
#pragma unroll
    for (int r = 0; r < 4; ++r) {
      const float v = acc[ct][r];
      const float vOdd = __shfl(v, lane | 1);
      if ((lane & 1) == 0) {
        const int row = n0 + quad * 4 + r;
        z1b[(size_t)row * 64 + cg * 32 + ct * 8 + (mrow >> 1)] = pack_bf16x2(v, vOdd);
      }
    }
  }
}

// ---------------- agg1: hb = pack_bf16(dropout(relu(z1[n] + sum z1[adj] + b1))) ----------------
__global__ __launch_bounds__(256, 8) void agg1(
    const uint32_t* __restrict__ z1b, const int* __restrict__ adj,
    const int* __restrict__ cnt, const float* __restrict__ b1,
    const uint32_t* __restrict__ zpad, uint32_t* __restrict__ hb) {
  const int lane = threadIdx.x & 63;
  const int wid  = threadIdx.x >> 6;
  const int n = blockIdx.x * 4 + wid;

  const int va = adj[(size_t)n * kCap + lane];
  int d = __builtin_amdgcn_readfirstlane(cnt[n]);
  if (d > kCap) d = kCap;

  const uint32_t self = z1b[(size_t)n * 64 + lane];
  float a0x = unpk_lo(self), a0y = unpk_hi(self);
  float a1x = 0.f, a1y = 0.f, a2x = 0.f, a2y = 0.f, a3x = 0.f, a3y = 0.f;

  int e = 0;
  while (e < d) {
#pragma unroll
    for (int j = 0; j < 16; ++j) {
      const int ee = e + j;
      const int idx = __builtin_amdgcn_readlane(va, ee);
      const uint32_t* base = (ee < d) ? (z1b + (size_t)idx * 64) : zpad;  // scalar select
      const uint32_t v = base[lane];
      if ((j & 3) == 0)      { a0x += unpk_lo(v); a0y += unpk_hi(v); }
      else if ((j & 3) == 1) { a1x += unpk_lo(v); a1y += unpk_hi(v); }
      else if ((j & 3) == 2) { a2x += unpk_lo(v); a2y += unpk_hi(v); }
      else                   { a3x += unpk_lo(v); a3y += unpk_hi(v); }
    }
    e += 16;
  }

  const float2 bb = *reinterpret_cast<const float2*>(b1 + 2 * lane);
  float hx = fmaxf((a0x + a1x) + (a2x + a3x) + bb.x, 0.0f);
  float hy = fmaxf((a0y + a1y) + (a2y + a3y) + bb.y, 0.0f);
  const uint32_t j0 = (uint32_t)n * 128u + 2u * (uint32_t)lane;
  hx = drop_elem(j0)      ? 0.0f : hx * 2.0f;
  hy = drop_elem(j0 + 1u) ? 0.0f : hy * 2.0f;
  hb[(size_t)n * 64 + lane] = pack_bf16x2(hx, hy);
}

// ---------------- GEMM2 (MFMA): z2b = pack_bf16(h @ W2) ----------------
// Wave = 16 rows x 64 cols (all of N). A-fragment = 4 consecutive dwords of hb
// (already packed bf16 pairs) -> one dwordx4, zero conversion.
__global__ __launch_bounds__(256, 4) void gemm2_mfma(
    const uint32_t* __restrict__ hb, const uint32_t* __restrict__ W2T,
    uint32_t* __restrict__ z2b) {
  __shared__ uint32_t WT[64 * 68];  // 17 KB
  for (int v = threadIdx.x; v < 64 * 64; v += 256)
    WT[(v >> 6) * 68 + (v & 63)] = W2T[v];
  __syncthreads();

  const int lane = threadIdx.x & 63;
  const int wid  = threadIdx.x >> 6;
  const int rb   = blockIdx.x * 4 + wid;  // 782 blocks -> rb 0..3127
  if (rb >= 3125) return;
  const int n0   = rb * 16;
  const int quad = lane >> 4;
  const int mrow = lane & 15;

  const uint32_t* hp = hb + (size_t)(n0 + mrow) * 64 + quad * 4;
  f32x4 acc[4] = {{0.f,0.f,0.f,0.f},{0.f,0.f,0.f,0.f},{0.f,0.f,0.f,0.f},{0.f,0.f,0.f,0.f}};

#pragma unroll
  for (int kb = 0; kb < 4; ++kb) {
    FragU a;
    a.q = *reinterpret_cast<const uint4*>(hp + kb * 16);
#pragma unroll
    for (int ct = 0; ct < 4; ++ct) {
      const int n = ct * 16 + mrow;
      FragU b;
      b.q = *reinterpret_cast<const uint4*>(&WT[n * 68 + kb * 16 + quad * 4]);
      acc[ct] = __builtin_amdgcn_mfma_f32_16x16x32_bf16(a.f, b.f, acc[ct], 0, 0, 0);
    }
  }

#pragma unroll
  for (int ct = 0; ct < 4; ++ct) {
#pragma unroll
    for (int r = 0; r < 4; ++r) {
      const float v = acc[ct][r];
      const float vOdd = __shfl(v, lane | 1);
      if ((lane & 1) == 0) {
        const int row = n0 + quad * 4 + r;
        z2b[(size_t)row * 32 + ct * 8 + (mrow >> 1)] = pack_bf16x2(v, vOdd);
      }
    }
  }
}

// ---------------- agg2: out = z2[n] + sum z2[adj] + b2 (width 64, bf16 rows) ----------------
__global__ __launch_bounds__(256, 8) void agg_out(
    const uint32_t* __restrict__ z2b, const int* __restrict__ adj,
    const int* __restrict__ cnt, const float* __restrict__ b2,
    const uint32_t* __restrict__ zpad, float* __restrict__ out) {
  const int lane = threadIdx.x & 63;
  const int wid  = threadIdx.x >> 6;
  const int n = blockIdx.x * 4 + wid;
  const uint32_t sh = (uint32_t)(lane & 1) * 16u;
  const int word = lane >> 1;

  const int va = adj[(size_t)n * kCap + lane];
  int d = __builtin_amdgcn_readfirstlane(cnt[n]);
  if (d > kCap) d = kCap;

  float a0 = unpk_sh(z2b[(size_t)n * 32 + word], sh);  // self
  float a1 = 0.f, a2 = 0.f, a3 = 0.f;

  int e = 0;
  while (e < d) {
#pragma unroll
    for (int j = 0; j < 16; ++j) {
      const int ee = e + j;
      const int idx = __builtin_amdgcn_readlane(va, ee);
      const uint32_t* base = (ee < d) ? (z2b + (size_t)idx * 32) : zpad;  // scalar select
      const float v = unpk_sh(base[word], sh);
      if ((j & 3) == 0)      a0 += v;
      else if ((j & 3) == 1) a1 += v;
      else if ((j & 3) == 2) a2 += v;
      else                   a3 += v;
    }
    e += 16;
  }

  out[(size_t)n * 64 + lane] = (a0 + a1) + (a2 + a3) + b2[lane];
}

// ---------------- launch ----------------
extern "C" void kernel_launch(void* const* d_in, const int* in_sizes, int n_in,
                              void* d_out, int out_size, void* d_ws, size_t ws_size,
                              hipStream_t stream) {
  const float* x  = (const float*)d_in[0];
  const int*   ei = (const int*)d_in[1];
  const float* W1 = (const float*)d_in[2];
  const float* b1 = (const float*)d_in[3];
  const float* W2 = (const float*)d_in[4];
  const float* b2 = (const float*)d_in[5];
  float* out = (float*)d_out;

  const int E = in_sizes[1] / 2;  // edge_index is (2, E), int32 on device
  const int* src = ei;
  const int* dst = ei + E;

  // d_ws layout:
  uint32_t* zpad = (uint32_t*)d_ws;                        // 64 dwords = 256 B, zeroed
  int*      cnt  = (int*)((char*)d_ws + 256);              // 50000 ints
  int*      adj  = cnt + kN;                               // 50000*64 ints = 12.8 MB
  uint32_t* z1b  = (uint32_t*)(adj + (size_t)kN * kCap);   // 50000*64 dwords = 12.8 MB
  uint32_t* hb   = z1b + (size_t)kN * 64;                  // 50000*64 dwords = 12.8 MB
  uint32_t* z2b  = hb + (size_t)kN * 64;                   // 50000*32 dwords = 6.4 MB
  uint32_t* W1T  = z2b + (size_t)kN * 32;                  // 8192 dwords = 32 KB
  uint32_t* W2T  = W1T + 128 * 64;                         // 4096 dwords = 16 KB

  hipMemsetAsync(d_ws, 0, 256 + (size_t)kN * sizeof(int), stream);  // zpad + cnt
  prep_wT<<<48, 256, 0, stream>>>(W1, W2, W1T, W2T);
  build_adj<<<(E + 255) / 256, 256, 0, stream>>>(src, dst, cnt, adj, E);
  gemm1_mfma<<<1563, 256, 0, stream>>>(x, W1T, z1b);
  agg1<<<12500, 256, 0, stream>>>(z1b, adj, cnt, b1, zpad, hb);
  gemm2_mfma<<<782, 256, 0, stream>>>(hb, W2T, z2b);
  agg_out<<<12500, 256, 0, stream>>>(z2b, adj, cnt, b2, zpad, out);
}

// Round 9
// 185.645 us; speedup vs baseline: 1.4355x; 1.0103x over previous
//
#include <hip/hip_runtime.h>
#include <stdint.h>

static constexpr int kN   = 50000;   // nodes
static constexpr int kCap = 64;      // adjacency capacity per node (Poisson(12) tail @64 ~ 1e-25)

typedef __attribute__((ext_vector_type(8))) _Float16 f16x8;  // MFMA A/B fragment
typedef __attribute__((ext_vector_type(2))) _Float16 f16x2;  // packed pair -> v_pk_add_f16
typedef __attribute__((ext_vector_type(4))) float f32x4;     // MFMA 16x16 accumulator

// ---------------- threefry2x32-20 (verified vs Random123 KAT) ----------------
__device__ __forceinline__ uint32_t rotl32(uint32_t v, uint32_t r) {
  return (v << r) | (v >> (32u - r));
}

__device__ __forceinline__ uint2 threefry2x32(uint32_t k0, uint32_t k1,
                                              uint32_t x0, uint32_t x1) {
  const uint32_t k2 = k0 ^ k1 ^ 0x1BD11BDAu;
  x0 += k0; x1 += k1;
#define TFR(r) { x0 += x1; x1 = rotl32(x1, r); x1 ^= x0; }
  TFR(13u) TFR(15u) TFR(26u) TFR(6u)
  x0 += k1; x1 += k2 + 1u;
  TFR(17u) TFR(29u) TFR(16u) TFR(24u)
  x0 += k2; x1 += k0 + 2u;
  TFR(13u) TFR(15u) TFR(26u) TFR(6u)
  x0 += k0; x1 += k1 + 3u;
  TFR(17u) TFR(29u) TFR(16u) TFR(24u)
  x0 += k1; x1 += k2 + 4u;
  TFR(13u) TFR(15u) TFR(26u) TFR(6u)
  x0 += k2; x1 += k0 + 5u;
#undef TFR
  return make_uint2(x0, x1);
}

__device__ __forceinline__ bool drop_elem(uint32_t j) {
  const uint2 r = threefry2x32(0u, 42u, 0u, j);
  return ((r.x ^ r.y) >> 31) != 0u;
}

// ---------------- f16 pack/unpack ----------------
union PairU { f16x2 h; uint32_t u; };
__device__ __forceinline__ uint32_t pack_f16x2(float lo, float hi) {
  PairU p; p.h[0] = (_Float16)lo; p.h[1] = (_Float16)hi; return p.u;
}
__device__ __forceinline__ float f16_lo(f16x2 v) { return (float)v[0]; }
__device__ __forceinline__ float f16_hi(f16x2 v) { return (float)v[1]; }

union FragU { uint4 q; f16x8 f; };

// ---------------- adjacency build: adj[d*64 + slot] = src ----------------
__global__ __launch_bounds__(256) void build_adj(
    const int* __restrict__ src, const int* __restrict__ dst,
    int* __restrict__ cnt, int* __restrict__ adj, int E) {
  int e = blockIdx.x * 256 + threadIdx.x;
  if (e >= E) return;
  int d = dst[e];
  int slot = atomicAdd(&cnt[d], 1);
  if (slot < kCap) adj[d * kCap + slot] = src[e];
}

// ---------------- prep: transpose+pack weights to f16 ----------------
// W1T[n*64+i] = pack(W1[2i][n], W1[2i+1][n])   (n<128, i<64)
// W2T[n*64+i] = pack(W2[2i][n], W2[2i+1][n])   (n<64,  i<64)
__global__ __launch_bounds__(256) void prep_wT(
    const float* __restrict__ W1, const float* __restrict__ W2,
    uint32_t* __restrict__ W1T, uint32_t* __restrict__ W2T) {
  int v = blockIdx.x * 256 + threadIdx.x;
  if (v < 128 * 64) {
    const int n = v >> 6, i = v & 63;
    W1T[v] = pack_f16x2(W1[(size_t)(2 * i) * 128 + n], W1[(size_t)(2 * i + 1) * 128 + n]);
  } else if (v < 128 * 64 + 64 * 64) {
    const int w = v - 128 * 64;
    const int n = w >> 6, i = w & 63;
    W2T[w] = pack_f16x2(W2[(size_t)(2 * i) * 64 + n], W2[(size_t)(2 * i + 1) * 64 + n]);
  }
}

// ---------------- GEMM1 (MFMA f16): z1h = pack_f16(x @ W1) ----------------
// Wave = 16 rows x 64 cols: 4 kb x 4 ct MFMAs. A: x converted to f16 in-flight.
// B: W1T staged in LDS, row stride 68 dwords (bank stride 4 -> 2-way, free).
// Layouts (HW-verified r8): A[m=lane&15][k=quad*8+j], B[n=lane&15][k=quad*8+j],
// D: col=lane&15, row=quad*4+reg.
__global__ __launch_bounds__(256, 4) void gemm1_mfma(
    const float* __restrict__ x, const uint32_t* __restrict__ W1T,
    uint32_t* __restrict__ z1h) {
  __shared__ uint32_t WT[128 * 68];  // 34 KB
  for (int v = threadIdx.x; v < 128 * 64; v += 256)
    WT[(v >> 6) * 68 + (v & 63)] = W1T[v];
  __syncthreads();

  const int lane = threadIdx.x & 63;
  const int wid  = threadIdx.x >> 6;
  const int rb   = blockIdx.x * 2 + (wid >> 1);  // 1563 blocks -> rb 0..3125
  if (rb >= 3125) return;                        // tail wave (after LDS build)
  const int cg   = wid & 1;                      // column group: cols cg*64..+63
  const int n0   = rb * 16;
  const int quad = lane >> 4;
  const int mrow = lane & 15;

  const float* xp = x + (size_t)(n0 + mrow) * 128 + quad * 8;
  f32x4 acc[4] = {{0.f,0.f,0.f,0.f},{0.f,0.f,0.f,0.f},{0.f,0.f,0.f,0.f},{0.f,0.f,0.f,0.f}};

#pragma unroll
  for (int kb = 0; kb < 4; ++kb) {
    const float4 lo = *reinterpret_cast<const float4*>(xp + kb * 32);
    const float4 hi = *reinterpret_cast<const float4*>(xp + kb * 32 + 4);
    FragU a;
    a.q = make_uint4(pack_f16x2(lo.x, lo.y), pack_f16x2(lo.z, lo.w),
                     pack_f16x2(hi.x, hi.y), pack_f16x2(hi.z, hi.w));
#pragma unroll
    for (int ct = 0; ct < 4; ++ct) {
      const int n = cg * 64 + ct * 16 + mrow;
      FragU b;
      b.q = *reinterpret_cast<const uint4*>(&WT[n * 68 + kb * 16 + quad * 4]);
      acc[ct] = __builtin_amdgcn_mfma_f32_16x16x32_f16(a.f, b.f, acc[ct], 0, 0, 0);
    }
  }

#pragma unroll
  for (int ct = 0; ct < 4; ++ct) {
#pragma unroll
    for (int r = 0; r < 4; ++r) {
      const float v = acc[ct][r];
      const float vOdd = __shfl(v, lane | 1);
      if ((lane & 1) == 0) {
        const int row = n0 + quad * 4 + r;
        z1h[(size_t)row * 64 + cg * 32 + ct * 8 + (mrow >> 1)] = pack_f16x2(v, vOdd);
      }
    }
  }
}

// ---------------- agg1: hh = pack_f16(dropout(relu(z1[n] + sum z1[adj] + b1))) ----------------
// Pure gather, no LDS. One node per wave; loop body = 1 load + 1 v_pk_add_f16.
__global__ __launch_bounds__(256, 8) void agg1(
    const f16x2* __restrict__ z1h, const int* __restrict__ adj,
    const int* __restrict__ cnt, const float* __restrict__ b1,
    const f16x2* __restrict__ zpad, uint32_t* __restrict__ hh) {
  const int lane = threadIdx.x & 63;
  const int wid  = threadIdx.x >> 6;
  const int n = blockIdx.x * 4 + wid;

  const int va = adj[(size_t)n * kCap + lane];
  int d = __builtin_amdgcn_readfirstlane(cnt[n]);
  if (d > kCap) d = kCap;

  f16x2 a0 = z1h[(size_t)n * 64 + lane];  // self
  f16x2 a1 = (f16x2)0, a2 = (f16x2)0, a3 = (f16x2)0;

  int e = 0;
  while (e < d) {
#pragma unroll
    for (int j = 0; j < 16; ++j) {
      const int ee = e + j;
      const int idx = __builtin_amdgcn_readlane(va, ee);
      const f16x2* base = (ee < d) ? (z1h + (size_t)idx * 64) : zpad;  // scalar select
      const f16x2 v = base[lane];
      if ((j & 3) == 0)      a0 += v;
      else if ((j & 3) == 1) a1 += v;
      else if ((j & 3) == 2) a2 += v;
      else                   a3 += v;
    }
    e += 16;
  }

  const f16x2 s = (a0 + a1) + (a2 + a3);
  const float2 bb = *reinterpret_cast<const float2*>(b1 + 2 * lane);
  float hx = fmaxf(f16_lo(s) + bb.x, 0.0f);
  float hy = fmaxf(f16_hi(s) + bb.y, 0.0f);
  const uint32_t j0 = (uint32_t)n * 128u + 2u * (uint32_t)lane;
  hx = drop_elem(j0)      ? 0.0f : hx * 2.0f;
  hy = drop_elem(j0 + 1u) ? 0.0f : hy * 2.0f;
  hh[(size_t)n * 64 + lane] = pack_f16x2(hx, hy);
}

// ---------------- GEMM2 (MFMA f16): z2h = pack_f16(h @ W2) ----------------
// A-fragment = 4 consecutive dwords of hh (already packed f16 pairs).
__global__ __launch_bounds__(256, 4) void gemm2_mfma(
    const uint32_t* __restrict__ hh, const uint32_t* __restrict__ W2T,
    uint32_t* __restrict__ z2h) {
  __shared__ uint32_t WT[64 * 68];  // 17 KB
  for (int v = threadIdx.x; v < 64 * 64; v += 256)
    WT[(v >> 6) * 68 + (v & 63)] = W2T[v];
  __syncthreads();

  const int lane = threadIdx.x & 63;
  const int wid  = threadIdx.x >> 6;
  const int rb   = blockIdx.x * 4 + wid;  // 782 blocks -> rb 0..3127
  if (rb >= 3125) return;
  const int n0   = rb * 16;
  const int quad = lane >> 4;
  const int mrow = lane & 15;

  const uint32_t* hp = hh + (size_t)(n0 + mrow) * 64 + quad * 4;
  f32x4 acc[4] = {{0.f,0.f,0.f,0.f},{0.f,0.f,0.f,0.f},{0.f,0.f,0.f,0.f},{0.f,0.f,0.f,0.f}};

#pragma unroll
  for (int kb = 0; kb < 4; ++kb) {
    FragU a;
    a.q = *reinterpret_cast<const uint4*>(hp + kb * 16);
#pragma unroll
    for (int ct = 0; ct < 4; ++ct) {
      const int n = ct * 16 + mrow;
      FragU b;
      b.q = *reinterpret_cast<const uint4*>(&WT[n * 68 + kb * 16 + quad * 4]);
      acc[ct] = __builtin_amdgcn_mfma_f32_16x16x32_f16(a.f, b.f, acc[ct], 0, 0, 0);
    }
  }

#pragma unroll
  for (int ct = 0; ct < 4; ++ct) {
#pragma unroll
    for (int r = 0; r < 4; ++r) {
      const float v = acc[ct][r];
      const float vOdd = __shfl(v, lane | 1);
      if ((lane & 1) == 0) {
        const int row = n0 + quad * 4 + r;
        z2h[(size_t)row * 32 + ct * 8 + (mrow >> 1)] = pack_f16x2(v, vOdd);
      }
    }
  }
}

// ---------------- agg2: out = z2[n] + sum z2[adj] + b2 (width 64, f16 rows) ----------------
// Row = 32 dwords (128 B). All 64 lanes accumulate word (lane&31) packed
// (lanes 32-63 mirror 0-31, same lines); one end shuffle unpacks feature lane.
__global__ __launch_bounds__(256, 8) void agg_out(
    const f16x2* __restrict__ z2h, const int* __restrict__ adj,
    const int* __restrict__ cnt, const float* __restrict__ b2,
    const f16x2* __restrict__ zpad, float* __restrict__ out) {
  const int lane = threadIdx.x & 63;
  const int wid  = threadIdx.x >> 6;
  const int n = blockIdx.x * 4 + wid;
  const int word = lane & 31;

  const int va = adj[(size_t)n * kCap + lane];
  int d = __builtin_amdgcn_readfirstlane(cnt[n]);
  if (d > kCap) d = kCap;

  f16x2 a0 = z2h[(size_t)n * 32 + word];  // self
  f16x2 a1 = (f16x2)0, a2 = (f16x2)0, a3 = (f16x2)0;

  int e = 0;
  while (e < d) {
#pragma unroll
    for (int j = 0; j < 16; ++j) {
      const int ee = e + j;
      const int idx = __builtin_amdgcn_readlane(va, ee);
      const f16x2* base = (ee < d) ? (z2h + (size_t)idx * 32) : zpad;  // scalar select
      const f16x2 v = base[word];
      if ((j & 3) == 0)      a0 += v;
      else if ((j & 3) == 1) a1 += v;
      else if ((j & 3) == 2) a2 += v;
      else                   a3 += v;
    }
    e += 16;
  }

  PairU s; s.h = (a0 + a1) + (a2 + a3);
  // feature `lane` lives in half (lane&1) of word (lane>>1), held by lane (lane>>1)
  PairU g; g.u = (uint32_t)__shfl((int)s.u, lane >> 1);
  const float v = (lane & 1) ? f16_hi(g.h) : f16_lo(g.h);
  out[(size_t)n * 64 + lane] = v + b2[lane];
}

// ---------------- launch ----------------
extern "C" void kernel_launch(void* const* d_in, const int* in_sizes, int n_in,
                              void* d_out, int out_size, void* d_ws, size_t ws_size,
                              hipStream_t stream) {
  const float* x  = (const float*)d_in[0];
  const int*   ei = (const int*)d_in[1];
  const float* W1 = (const float*)d_in[2];
  const float* b1 = (const float*)d_in[3];
  const float* W2 = (const float*)d_in[4];
  const float* b2 = (const float*)d_in[5];
  float* out = (float*)d_out;

  const int E = in_sizes[1] / 2;  // edge_index is (2, E), int32 on device
  const int* src = ei;
  const int* dst = ei + E;

  // d_ws layout:
  uint32_t* zpad = (uint32_t*)d_ws;                        // 64 dwords = 256 B, zeroed
  int*      cnt  = (int*)((char*)d_ws + 256);              // 50000 ints
  int*      adj  = cnt + kN;                               // 50000*64 ints = 12.8 MB
  uint32_t* z1h  = (uint32_t*)(adj + (size_t)kN * kCap);   // 50000*64 dwords = 12.8 MB
  uint32_t* hh   = z1h + (size_t)kN * 64;                  // 50000*64 dwords = 12.8 MB
  uint32_t* z2h  = hh + (size_t)kN * 64;                   // 50000*32 dwords = 6.4 MB
  uint32_t* W1T  = z2h + (size_t)kN * 32;                  // 8192 dwords = 32 KB
  uint32_t* W2T  = W1T + 128 * 64;                         // 4096 dwords = 16 KB

  hipMemsetAsync(d_ws, 0, 256 + (size_t)kN * sizeof(int), stream);  // zpad + cnt
  prep_wT<<<48, 256, 0, stream>>>(W1, W2, W1T, W2T);
  build_adj<<<(E + 255) / 256, 256, 0, stream>>>(src, dst, cnt, adj, E);
  gemm1_mfma<<<1563, 256, 0, stream>>>(x, W1T, z1h);
  agg1<<<12500, 256, 0, stream>>>((const f16x2*)z1h, adj, cnt, b1, (const f16x2*)zpad, hh);
  gemm2_mfma<<<782, 256, 0, stream>>>(hh, W2T, z2h);
  agg_out<<<12500, 256, 0, stream>>>((const f16x2*)z2h, adj, cnt, b2, (const f16x2*)zpad, out);
}